// Round 3
// baseline (138.040 us; speedup 1.0000x reference)
//
#include <hip/hip_runtime.h>

// Problem constants (from reference setup_inputs)
#define NUM_TOKENS 32768
#define HIDDEN     2048
#define IVS        32000
#define SLOTS      64
#define MAX_HYPER  1024
#define BINS       (IVS + MAX_HYPER)   // 33024 possible ids

typedef float f32x4 __attribute__((ext_vector_type(4)));

// ---------- counting sort by token id ----------

__global__ __launch_bounds__(256)
void zero_hist_kernel(int* __restrict__ hist) {
    int i = blockIdx.x * 256 + threadIdx.x;
    if (i < BINS) hist[i] = 0;
}

__global__ __launch_bounds__(256)
void hist_kernel(const int* __restrict__ input_, int* __restrict__ hist) {
    int t = blockIdx.x * 256 + threadIdx.x;
    if (t < NUM_TOKENS) {
        int id = input_[t];
        if (id < 0) id = 0; else if (id >= BINS) id = BINS - 1;
        atomicAdd(&hist[id], 1);
    }
}

// Single-block exclusive scan over BINS counts (in place: counts -> starts).
#define SCAN_T 1024
#define SCAN_C ((BINS + SCAN_T - 1) / SCAN_T)   // 33

__global__ __launch_bounds__(SCAN_T)
void scan_kernel(int* __restrict__ hist) {
    __shared__ int tot[SCAN_T];
    const int t = threadIdx.x;
    const int base = t * SCAN_C;

    int sum = 0;
    for (int i = 0; i < SCAN_C; ++i) {
        int idx = base + i;
        if (idx < BINS) sum += hist[idx];
    }
    tot[t] = sum;
    __syncthreads();

    // Hillis-Steele inclusive scan in LDS
    for (int off = 1; off < SCAN_T; off <<= 1) {
        int v = 0;
        if (t >= off) v = tot[t - off];
        __syncthreads();
        if (t >= off) tot[t] += v;
        __syncthreads();
    }
    int run = tot[t] - sum;   // exclusive prefix for this chunk

    for (int i = 0; i < SCAN_C; ++i) {
        int idx = base + i;
        if (idx < BINS) {
            int v = hist[idx];
            hist[idx] = run;   // start offset
            run += v;
        }
    }
}

__global__ __launch_bounds__(256)
void scatter_kernel(const int* __restrict__ input_,
                    int* __restrict__ cursor,       // starts, consumed by atomic inc
                    int* __restrict__ sorted) {
    int t = blockIdx.x * 256 + threadIdx.x;
    if (t < NUM_TOKENS) {
        int id = input_[t];
        if (id < 0) id = 0; else if (id >= BINS) id = BINS - 1;
        int pos = atomicAdd(&cursor[id], 1);
        sorted[pos] = t;
    }
}

// ---------- main copy: one wave per (sorted) token ----------

__global__ __launch_bounds__(256)
void copy_kernel(const int*   __restrict__ sorted,
                 const int*   __restrict__ input_,
                 const int*   __restrict__ t2b,
                 const int*   __restrict__ pool_idx,
                 const float* __restrict__ weight,
                 const float* __restrict__ ebuf,
                 float*       __restrict__ out)
{
    const int wave  = threadIdx.x >> 6;            // 0..3
    const int lane  = threadIdx.x & 63;
    const int gidx  = (blockIdx.x << 2) + wave;
    const int token = sorted[gidx];

    const int id = input_[token];

    const f32x4* src = nullptr;
    if (id < IVS) {
        src = reinterpret_cast<const f32x4*>(weight + (size_t)id * HIDDEN);
    } else {
        const int hid = id - IVS;
        if (hid < MAX_HYPER) {
            const int slot = pool_idx[t2b[token]];
            src = reinterpret_cast<const f32x4*>(
                ebuf + ((size_t)slot * MAX_HYPER + (size_t)hid) * HIDDEN);
        }
    }

    f32x4* dst = reinterpret_cast<f32x4*>(out + (size_t)token * HIDDEN);

    if (src) {
        f32x4 v[8];
        #pragma unroll
        for (int j = 0; j < 8; ++j) v[j] = src[lane + j * 64];
        #pragma unroll
        for (int j = 0; j < 8; ++j)
            __builtin_nontemporal_store(v[j], &dst[lane + j * 64]);
    } else {
        const f32x4 z = {0.f, 0.f, 0.f, 0.f};
        #pragma unroll
        for (int j = 0; j < 8; ++j)
            __builtin_nontemporal_store(z, &dst[lane + j * 64]);
    }
}

// ---------- fallback (no workspace): direct unsorted copy ----------

__global__ __launch_bounds__(256)
void copy_direct_kernel(const int*   __restrict__ input_,
                        const int*   __restrict__ t2b,
                        const int*   __restrict__ pool_idx,
                        const float* __restrict__ weight,
                        const float* __restrict__ ebuf,
                        float*       __restrict__ out)
{
    const int wave  = threadIdx.x >> 6;
    const int lane  = threadIdx.x & 63;
    const int token = (blockIdx.x << 2) + wave;

    const int id = input_[token];
    const f32x4* src = nullptr;
    if (id < IVS) {
        src = reinterpret_cast<const f32x4*>(weight + (size_t)id * HIDDEN);
    } else {
        const int hid = id - IVS;
        if (hid < MAX_HYPER) {
            const int slot = pool_idx[t2b[token]];
            src = reinterpret_cast<const f32x4*>(
                ebuf + ((size_t)slot * MAX_HYPER + (size_t)hid) * HIDDEN);
        }
    }
    f32x4* dst = reinterpret_cast<f32x4*>(out + (size_t)token * HIDDEN);
    if (src) {
        f32x4 v[8];
        #pragma unroll
        for (int j = 0; j < 8; ++j) v[j] = src[lane + j * 64];
        #pragma unroll
        for (int j = 0; j < 8; ++j)
            __builtin_nontemporal_store(v[j], &dst[lane + j * 64]);
    } else {
        const f32x4 z = {0.f, 0.f, 0.f, 0.f};
        #pragma unroll
        for (int j = 0; j < 8; ++j)
            __builtin_nontemporal_store(z, &dst[lane + j * 64]);
    }
}

extern "C" void kernel_launch(void* const* d_in, const int* in_sizes, int n_in,
                              void* d_out, int out_size, void* d_ws, size_t ws_size,
                              hipStream_t stream) {
    const int*   input_ = (const int*)d_in[0];
    const int*   t2b    = (const int*)d_in[1];
    const int*   pool   = (const int*)d_in[2];
    const float* weight = (const float*)d_in[3];
    const float* ebuf   = (const float*)d_in[4];
    float*       out    = (float*)d_out;

    const size_t need = (size_t)BINS * 4 + (size_t)NUM_TOKENS * 4;
    if (ws_size >= need) {
        int* hist   = (int*)d_ws;                   // BINS ints
        int* sorted = hist + BINS;                  // NUM_TOKENS ints

        zero_hist_kernel<<<(BINS + 255) / 256, 256, 0, stream>>>(hist);
        hist_kernel<<<NUM_TOKENS / 256, 256, 0, stream>>>(input_, hist);
        scan_kernel<<<1, SCAN_T, 0, stream>>>(hist);
        scatter_kernel<<<NUM_TOKENS / 256, 256, 0, stream>>>(input_, hist, sorted);
        copy_kernel<<<NUM_TOKENS / 4, 256, 0, stream>>>(
            sorted, input_, t2b, pool, weight, ebuf, out);
    } else {
        copy_direct_kernel<<<NUM_TOKENS / 4, 256, 0, stream>>>(
            input_, t2b, pool, weight, ebuf, out);
    }
}

// Round 4
// 82.729 us; speedup vs baseline: 1.6686x; 1.6686x over previous
//
#include <hip/hip_runtime.h>

// Problem constants (from reference setup_inputs)
#define NUM_TOKENS 32768
#define HIDDEN     2048
#define IVS        32000
#define SLOTS      64
#define MAX_HYPER  1024

typedef float f32x4 __attribute__((ext_vector_type(4)));

// One WAVE (64 lanes) per token: branch is wave-uniform; each lane moves
// 8 x float4 = 128 B. 4 tokens per 256-thread block -> 8192 blocks.
// Output stores are non-temporal (write-once) so they don't evict the
// gathered rows from L2/L3 -- duplicate token ids then re-hit cache.
//
// R3 post-mortem: a device-side counting sort by id (to force duplicate
// temporal locality) cost ~30 us of small-kernel/latency overhead AND made
// the copy itself slower (XCD/channel hotspotting on same-id adjacency).
// Random order + NT stores already lets L3 absorb duplicate reads. This
// direct form is the roofline configuration: ~536 MB worst-case at
// 6.5 TB/s ~= 95% of the pure-write fill-kernel BW on this chip.
__global__ __launch_bounds__(256)
void zip2zip_embed_kernel(const int*   __restrict__ input_,
                          const int*   __restrict__ t2b,
                          const int*   __restrict__ pool_idx,
                          const float* __restrict__ weight,
                          const float* __restrict__ ebuf,
                          float*       __restrict__ out)
{
    const int wave  = threadIdx.x >> 6;            // 0..3
    const int lane  = threadIdx.x & 63;
    const int token = (blockIdx.x << 2) + wave;

    const int id = input_[token];

    const f32x4* src = nullptr;
    if (id < IVS) {
        src = reinterpret_cast<const f32x4*>(weight + (size_t)id * HIDDEN);
    } else {
        const int hid = id - IVS;
        if (hid < MAX_HYPER) {   // always true for this input range; kept for safety
            const int slot = pool_idx[t2b[token]];
            src = reinterpret_cast<const f32x4*>(
                ebuf + ((size_t)slot * MAX_HYPER + (size_t)hid) * HIDDEN);
        }
    }

    f32x4* dst = reinterpret_cast<f32x4*>(out + (size_t)token * HIDDEN);

    if (src) {
        f32x4 v[8];
        #pragma unroll
        for (int j = 0; j < 8; ++j) {
            v[j] = src[lane + j * 64];
        }
        #pragma unroll
        for (int j = 0; j < 8; ++j) {
            __builtin_nontemporal_store(v[j], &dst[lane + j * 64]);
        }
    } else {
        const f32x4 z = {0.f, 0.f, 0.f, 0.f};
        #pragma unroll
        for (int j = 0; j < 8; ++j) {
            __builtin_nontemporal_store(z, &dst[lane + j * 64]);
        }
    }
}

extern "C" void kernel_launch(void* const* d_in, const int* in_sizes, int n_in,
                              void* d_out, int out_size, void* d_ws, size_t ws_size,
                              hipStream_t stream) {
    // setup_inputs order:
    //   0: input_                     [NUM_TOKENS] int32
    //   1: token_to_batch_indices     [NUM_TOKENS] int32
    //   2: hyper_weight_pool_indices  [BATCH]      int32
    //   3: weight                     [IVS, HIDDEN]              float32
    //   4: embedding_buffer           [SLOTS, MAX_HYPER, HIDDEN] float32
    const int*   input_ = (const int*)d_in[0];
    const int*   t2b    = (const int*)d_in[1];
    const int*   pool   = (const int*)d_in[2];
    const float* weight = (const float*)d_in[3];
    const float* ebuf   = (const float*)d_in[4];
    float*       out    = (float*)d_out;

    zip2zip_embed_kernel<<<NUM_TOKENS / 4, 256, 0, stream>>>(
        input_, t2b, pool, weight, ebuf, out);
}